// Round 8
// baseline (9.506 us; speedup 1.0000x reference)
//
#include <hip/hip_runtime.h>
#include <math.h>

// GNN_59219009077824  — B=1024, N=256, F=6, H=128, O=64
//
// Low-rank structure: edge(i,j) = cond_i | cond_j among valid nodes.
// C = valid & cond, NC = valid & !cond.
//   dinv = a = nv^-0.5 for C;  dinv = c = (nc+1)^-0.5 for NC.
// (An Y)_i = a*S_all for i in C;  c*S_c + c^2*Y_i for i in NC.
// out[o] = (alpha*y2C[o] + beta*y2N[o])/nv + b2[o],
//   alpha = a*nc*(nc*a+(nv-nc)*c), beta = c*(nc*a+c)
//   -> single matvec over g[h] = (alpha*hC[h] + beta*hN[h])/nv.
// R1: LDS atomics -> ballot/shuffle (20.0 -> 13.6 us).
// R2-4: DPP wave reduction + weight prefetch (13.6 -> 11.8 us).
// R5: one wave per batch (11.8 -> 9.9 us).
// R6: zero-LDS readlane matvec (10.2 — neutral; latency-bound, no TLP).
// R7: two waves per batch, 2 waves/SIMD (9.4 us).
// R8: FOUR waves per batch (1 node/thread) — 4 waves/SIMD TLP, per-wave
//     serial path halved again: 3 x-loads, 32 W2 regs, 8x b128 g-reads.

#define NB 1024
#define NN 256
#define NF 6
#define NH 128
#define NO 64

// v_add_f32 with DPP-moved operand; old=0 so masked-off lanes add 0.
template <int CTRL, int ROW_MASK, int BANK_MASK>
__device__ __forceinline__ float dpp_add(float v) {
    int moved = __builtin_amdgcn_update_dpp(0, __float_as_int(v),
                                            CTRL, ROW_MASK, BANK_MASK, true);
    return v + __int_as_float(moved);
}

// Full 64-lane sum; result valid in lane 63. Canonical gfx9 DPP sequence.
__device__ __forceinline__ float wave_sum64(float v) {
    v = dpp_add<0x111, 0xf, 0xf>(v); // row_shr:1
    v = dpp_add<0x112, 0xf, 0xf>(v); // row_shr:2
    v = dpp_add<0x114, 0xf, 0xe>(v); // row_shr:4
    v = dpp_add<0x118, 0xf, 0xc>(v); // row_shr:8
    v = dpp_add<0x142, 0xa, 0xf>(v); // row_bcast:15
    v = dpp_add<0x143, 0xc, 0xf>(v); // row_bcast:31
    return v;
}

__global__ __launch_bounds__(256) void gnn_kernel(
    const float* __restrict__ x,    // [B,N,F]
    const float* __restrict__ W1,   // [F,H]
    const float* __restrict__ b1,   // [H]
    const float* __restrict__ W2,   // [H,O]
    const float* __restrict__ b2,   // [O]
    float* __restrict__ out)        // [B,O]
{
    const int b    = blockIdx.x;
    const int t    = threadIdx.x;
    const int wid  = t >> 6;        // 0..3
    const int lane = t & 63;
    const int h    = t & (NH - 1);  // layer-1 channel (computed twice)

    __shared__ float  psum[4][16];   // per-wave reduced sums + counts
    __shared__ float4 xc4[NN][2];    // NC-compacted features, per-wave segments
    __shared__ float  g_lds[NH];     // fused layer-1 result
    __shared__ float  hN2[2][NH];    // NC-acc halves (general case only)
    __shared__ float  ypart[4][NO];  // per-wave partial outputs

    // ---- Entry prefetches: x (HBM) first, then W2 col, W1 row ----
    const float2* xp = (const float2*)(x + (size_t)b * NN * NF + (size_t)t * NF);
    const float2 u0 = xp[0], u1 = xp[1], u2 = xp[2];

    float w2r[32];                   // W2[32*wid+i][lane]
    #pragma unroll
    for (int i = 0; i < 32; ++i)
        w2r[i] = W2[(size_t)((wid * 32 + i) * NO) + lane];

    float w1r[NF];
    #pragma unroll
    for (int f = 0; f < NF; ++f) w1r[f] = W1[f * NH + h];
    const float b1r = b1[h];
    const float b2r = b2[lane];

    // ---- Classify this thread's single node ----
    const float xf[NF] = { u0.x, u0.y, u1.x, u1.y, u2.x, u2.y };
    const float absum = fabsf(xf[0]) + fabsf(xf[1]) + fabsf(xf[2])
                      + fabsf(xf[3]) + fabsf(xf[4]) + fabsf(xf[5]);
    const bool valid = (absum != 0.f);
    const bool condv = valid && ((xf[3] != 0.f) || (xf[4] != 0.f));
    const bool isNC  = valid && !condv;

    const unsigned long long mV = __ballot(valid);
    const unsigned long long mC = __ballot(condv);
    const unsigned long long mN = __ballot(isNC);

    float r[12];
    #pragma unroll
    for (int f = 0; f < NF; ++f) {
        r[f]     = condv ? xf[f] : 0.f;
        r[f + 6] = isNC  ? xf[f] : 0.f;
    }
    #pragma unroll
    for (int j = 0; j < 12; ++j) r[j] = wave_sum64(r[j]);

    if (lane == 63) {
        #pragma unroll
        for (int j = 0; j < 12; ++j) psum[wid][j] = r[j];
        psum[wid][12] = (float)__popcll(mV);
        psum[wid][13] = (float)__popcll(mC);
        psum[wid][14] = (float)__popcll(mN);
    }
    // NC compaction into this wave's private segment (order irrelevant)
    if (isNC) {
        const int rank = (int)__popcll(mN & ((1ull << lane) - 1ull));
        xc4[wid * 64 + rank][0] = make_float4(xf[0], xf[1], xf[2], xf[3]);
        xc4[wid * 64 + rank][1] = make_float4(xf[4], xf[5], 0.f, 0.f);
    }
    __syncthreads();

    // ---- Combine per-wave partials (broadcast LDS reads) ----
    float fs[12];
    #pragma unroll
    for (int j = 0; j < 12; ++j)
        fs[j] = psum[0][j] + psum[1][j] + psum[2][j] + psum[3][j];
    const int nv = (int)(psum[0][12] + psum[1][12] + psum[2][12] + psum[3][12]);
    const int nc = (int)(psum[0][13] + psum[1][13] + psum[2][13] + psum[3][13]);
    const int nncw0 = (int)psum[0][14], nncw1 = (int)psum[1][14];
    const int nncw2 = (int)psum[2][14], nncw3 = (int)psum[3][14];
    const int nnct  = nncw0 + nncw1 + nncw2 + nncw3;

    if (nv == 0) {                  // block-uniform; all threads return
        if (t < NO) out[(size_t)b * NO + t] = 0.f;
        return;
    }

    const float a  = 1.f / sqrtf((float)nv);
    const float c  = 1.f / sqrtf((float)(nc + 1));
    const float c2 = c * c;

    // ---- Layer 1 for channel h (each h computed by 2 threads) ----
    float zc = 0.f, zn = 0.f;
    #pragma unroll
    for (int f = 0; f < NF; ++f) {
        zc = fmaf(fs[f],     w1r[f], zc);
        zn = fmaf(fs[f + 6], w1r[f], zn);
    }
    const float Sc   = a * zc;
    const float Sall = Sc + c * zn;
    const float hC   = fmaxf(fmaf(a, Sall, b1r), 0.f);

    float acc = 0.f;                 // NC sum; empty in the bench case
    if (nnct > 0) {                  // block-uniform branch
        const float vloc = fmaf(c, Sc, b1r);
        const int   half = t >> 7;   // split 4 segments over thread halves
        const int   cnt[4] = { nncw0, nncw1, nncw2, nncw3 };
        for (int w = half * 2; w < half * 2 + 2; ++w) {
            const int n = cnt[w];
            for (int k = 0; k < n; ++k) {
                const float4 v0 = xc4[w * 64 + k][0];
                const float4 v1 = xc4[w * 64 + k][1];
                float z = v0.x * w1r[0];
                z = fmaf(v0.y, w1r[1], z);
                z = fmaf(v0.z, w1r[2], z);
                z = fmaf(v0.w, w1r[3], z);
                z = fmaf(v1.x, w1r[4], z);
                z = fmaf(v1.y, w1r[5], z);
                acc += fmaxf(fmaf(c2, z, vloc), 0.f);
            }
        }
        hN2[half][h] = acc;
        __syncthreads();
        acc = hN2[0][h] + hN2[1][h];
    }

    // ---- Fold aggregation-2 + pool into per-channel g ----
    const float alpha  = a * (float)nc * ((float)nc * a + (float)(nv - nc) * c);
    const float beta   = c * ((float)nc * a + c);
    const float inv_nv = 1.f / (float)nv;
    if (t < NH) g_lds[t] = (alpha * hC + beta * acc) * inv_nv;
    __syncthreads();

    // ---- Layer 2: wave handles 32 channels; g via broadcast b128 reads ----
    const float4* gv4 = (const float4*)(g_lds + wid * 32);
    float y0 = 0.f, y1 = 0.f;
    #pragma unroll
    for (int i4 = 0; i4 < 8; ++i4) {
        const float4 gv = gv4[i4];
        y0 = fmaf(gv.x, w2r[i4 * 4 + 0], y0);
        y1 = fmaf(gv.y, w2r[i4 * 4 + 1], y1);
        y0 = fmaf(gv.z, w2r[i4 * 4 + 2], y0);
        y1 = fmaf(gv.w, w2r[i4 * 4 + 3], y1);
    }
    const float y = y0 + y1;

    if (wid != 0) ypart[wid][lane] = y;
    __syncthreads();
    if (wid == 0)
        out[(size_t)b * NO + lane] =
            y + ypart[1][lane] + ypart[2][lane] + ypart[3][lane] + b2r;
}

extern "C" void kernel_launch(void* const* d_in, const int* in_sizes, int n_in,
                              void* d_out, int out_size, void* d_ws, size_t ws_size,
                              hipStream_t stream) {
    const float* x  = (const float*)d_in[0];
    const float* W1 = (const float*)d_in[1];
    const float* b1 = (const float*)d_in[2];
    const float* W2 = (const float*)d_in[3];
    const float* b2 = (const float*)d_in[4];
    float* out = (float*)d_out;

    gnn_kernel<<<NB, 256, 0, stream>>>(x, W1, b1, W2, b2, out);
}